// Round 1
// 639.974 us; speedup vs baseline: 1.0036x; 1.0036x over previous
//
#include <hip/hip_runtime.h>

typedef unsigned short u16;
typedef unsigned int u32;

typedef __attribute__((ext_vector_type(8))) short bf16x8;
typedef __attribute__((ext_vector_type(4))) float f32x4;

#define B_ 8
#define S_ 2048
#define H_ 8
#define ID_ 256
#define OD_ 256
#define K_ 512
#define M_ (B_*S_*H_)   /* 131072 */
#define N1_ 768
#define N2_ 256
#define G2_ 512          /* activated-gate tensor width: [ig(256) | f(256)] fp16 */

#define CSCH 64            /* cumsum chunks over S */
#define CSST (S_/CSCH)     /* 32 steps per chunk */

// ---- workspace layout (bytes) ----
#define OFF_X2   (0ull)
#define SZ_X2    ((unsigned long long)M_*K_*2)        /* 134,217,728 */
#define OFF_G    (OFF_X2 + SZ_X2)
#define SZ_G     ((unsigned long long)M_*G2_*2)       /* 134,217,728 */
#define OFF_WH   (OFF_G + SZ_G)
#define SZ_WH    ((unsigned long long)N1_*K_*2)
#define OFF_WO   (OFF_WH + SZ_WH)
#define SZ_WO    ((unsigned long long)N2_*K_*2)
#define OFF_AUX  (OFF_WO + SZ_WO)
#define SZ_AUX   ((unsigned long long)B_*CSCH*2048*4)
#define OFF_CF   (OFF_AUX + SZ_AUX)
#define SZ_CARR  ((unsigned long long)B_*H_*32*256*4)
#define OFF_CC   (OFF_CF + SZ_CARR)
#define OFF_CIN  (OFF_CC + SZ_CARR)
#define OFF_BR   (OFF_CIN + SZ_CARR)
#define SZ_BR    ((unsigned long long)N1_*4)

__device__ __forceinline__ u16 f2bf(float f) {
    union { float f; u32 u; } v; v.f = f;
    u32 u = v.u;
    u += 0x7fffu + ((u >> 16) & 1u);   // round-to-nearest-even
    return (u16)(u >> 16);
}
__device__ __forceinline__ float bf2f(u16 h) {
    union { u32 u; float f; } v; v.u = ((u32)h) << 16;
    return v.f;
}
__device__ __forceinline__ u32 pack2h(float a, float b) {
    union { _Float16 h; u16 u; } x, y;
    x.h = (_Float16)a; y.h = (_Float16)b;
    return (u32)x.u | ((u32)y.u << 16);
}
__device__ __forceinline__ float h2f(u16 u) {
    union { u16 u; _Float16 h; } v; v.u = u;
    return (float)v.h;
}
__device__ __forceinline__ float sigm(float x) {
    return 1.0f / (1.0f + __expf(-x));
}

// async 16B global->LDS DMA. LDS dest = wave-uniform base + lane*16.
__device__ __forceinline__ void gld16(const void* g, void* l) {
    __builtin_amdgcn_global_load_lds(
        (const __attribute__((address_space(1))) void*)g,
        (__attribute__((address_space(3))) void*)l, 16, 0, 0);
}

// W_hid row permutation: tiles 0-3 hold (i,h) interleaved pairs, tiles 4-5 f.
//   n < 512:  o = (n/128)*64 + (n%128)/2 ; src = (n&1) ? 512+o (hidden) : o (igate)
//   n >= 512: src = 256 + (n-512) (fgate)
__device__ __forceinline__ int whid_src_row(int n) {
    if (n < 512) {
        int o = ((n >> 7) << 6) + ((n & 127) >> 1);
        return (n & 1) ? (512 + o) : o;
    }
    return 256 + (n - 512);
}

// ---- 0: weights fp32 -> bf16 (W_hid rows permuted) + reordered hid bias ----
__global__ __launch_bounds__(256) void wconv_kernel(
    const float* __restrict__ Whid, const float* __restrict__ bhid,
    const float* __restrict__ Wog,
    u16* __restrict__ WhB, u16* __restrict__ WoB, float* __restrict__ br)
{
    int idx = blockIdx.x * 256 + threadIdx.x;
    if (idx < N1_*K_) {
        const int n = idx >> 9, k = idx & 511;
        WhB[idx] = f2bf(Whid[(size_t)whid_src_row(n) * K_ + k]);
    }
    if (idx < N2_*K_) WoB[idx] = f2bf(Wog[idx]);
    if (idx < N1_) br[idx] = bhid[whid_src_row(idx)];
}

// ---- 1: cumsum phase 1 — per-(b,chunk) local totals over CSST s-steps ----
__global__ __launch_bounds__(256) void csum_phase1(
    const float* __restrict__ X, float* __restrict__ aux)
{
    const int bch = blockIdx.x;          // b*CSCH + ch
    const int b = bch / CSCH, ch = bch % CSCH;
    const int t = threadIdx.x;
    float acc[8];
#pragma unroll
    for (int h = 0; h < 8; ++h) acc[h] = 0.f;
    for (int i = 0; i < CSST; ++i) {
        const int s = ch * CSST + i;
        const float* xp = X + ((size_t)(b * S_ + s)) * 2048 + t;
#pragma unroll
        for (int h = 0; h < 8; ++h) acc[h] += xp[h * 256];
    }
    float* ap = aux + (size_t)bch * 2048 + t;
#pragma unroll
    for (int h = 0; h < 8; ++h) ap[h * 256] = acc[h];
}

// ---- 2: cumsum carry — exclusive prefix over CSCH chunks, in place ----
__global__ __launch_bounds__(256) void csum_mid(float* __restrict__ aux)
{
    const int idx = blockIdx.x * 256 + threadIdx.x;
    const int b = idx >> 11, c = idx & 2047;
    float run = 0.f;
    for (int ch = 0; ch < CSCH; ++ch) {
        float* p = aux + ((size_t)(b * CSCH + ch)) * 2048 + c;
        float v = *p; *p = run; run += v;
    }
}

// ---- 3: cumsum phase 2 — replay + LayerNorm + pack x2 bf16 ----
__global__ __launch_bounds__(256) void csum_phase2(
    const float* __restrict__ X, const float* __restrict__ aux,
    const float* __restrict__ lnw, const float* __restrict__ lnb,
    u16* __restrict__ x2)
{
    const int bch = blockIdx.x;
    const int b = bch / CSCH, ch = bch % CSCH;
    const int t = threadIdx.x;
    float c[8], wv[8], bv[8];
#pragma unroll
    for (int h = 0; h < 8; ++h) {
        c[h]  = aux[(size_t)bch * 2048 + h * 256 + t];
        wv[h] = lnw[h * 256 + t];
        bv[h] = lnb[h * 256 + t];
    }
    __shared__ float red[2][4];
    for (int i = 0; i < CSST; ++i) {
        const int s = ch * CSST + i;
        const float* xp = X + ((size_t)(b * S_ + s)) * 2048 + t;
        float xa[8];
#pragma unroll
        for (int h = 0; h < 8; ++h) { xa[h] = xp[h * 256]; c[h] += xa[h]; }
        float sx = 0.f, sq = 0.f;
#pragma unroll
        for (int h = 0; h < 8; ++h) { sx += c[h]; sq += c[h] * c[h]; }
#pragma unroll
        for (int off = 32; off >= 1; off >>= 1) {
            sx += __shfl_down(sx, (unsigned)off);
            sq += __shfl_down(sq, (unsigned)off);
        }
        const int wid = t >> 6;
        if ((t & 63) == 0) { red[0][wid] = sx; red[1][wid] = sq; }
        __syncthreads();
        const float tsx = red[0][0] + red[0][1] + red[0][2] + red[0][3];
        const float tsq = red[1][0] + red[1][1] + red[1][2] + red[1][3];
        __syncthreads();
        const float mean = tsx * (1.f / 2048.f);
        const float var  = tsq * (1.f / 2048.f) - mean * mean;
        const float rstd = rsqrtf(var + 1e-6f);
        const size_t mrow = ((size_t)(b * S_ + s)) * H_;
#pragma unroll
        for (int h = 0; h < 8; ++h) {
            u16* row = x2 + (mrow + h) * (size_t)K_;
            row[t]       = f2bf(xa[h]);
            row[256 + t] = f2bf((c[h] - mean) * rstd * wv[h] + bv[h]);
        }
    }
}

// ---- GEMM: C[m,n] = sum_k A[m,k] * W[n,k], A/W bf16 row-major (ld=512) ----
// 128x128 tile, BK=64, 4 waves (2x2) x 64x64 each via 4x4 mfma_16x16x32_bf16.
// EPI==0 (GATE): apply gate nonlinearities from fp32 acc, write fp16 g'
//   pair tiles (tileN<4): cols (2j,2j+1)=(i_o,h_o) -> ig_o = sig(i)*relu(h)
//   f tiles (tileN>=4):   f_o = sig(f)
//   g' row layout: [ig_0..ig_255 | f_0..f_255]  (width G2_=512)
// EPI==1 (OG): fp32 out with sigmoid(x+b)*cell
template<int N, int EPI>
__global__ __launch_bounds__(256) void gemm_kernel(
    const u16* __restrict__ A, const u16* __restrict__ Bw,
    u16* __restrict__ Gout, const float* __restrict__ bias,
    const u16* __restrict__ cellbuf, float* __restrict__ Out)
{
    constexpr int NT = N / 128;
    const int blk = blockIdx.x;
    const int xcd = blk & 7;
    const int j = blk >> 3;
    const int tileN = j % NT;
    const int tileM = (j / NT) * 8 + xcd;
    const int m0 = tileM * 128, n0 = tileN * 128;
    const int tid = threadIdx.x;
    const int lane = tid & 63;
    const int w = tid >> 6, wm = w & 1, wn = w >> 1;
    const int l15 = lane & 15, quad = lane >> 4;

    __shared__ __align__(16) u16 smem[2 * 128 * 64];   // 32 KB
    u16* As = smem;
    u16* Bs = smem + 128 * 64;

    const int lane3 = lane >> 3;   // row-within-8-group
    const int pc = lane & 7;       // physical 16B chunk
    const int ra7 = l15 & 7;       // row&7 for fragment reads

    f32x4 acc[4][4];
    const f32x4 zero4 = {0.f, 0.f, 0.f, 0.f};
#pragma unroll
    for (int i = 0; i < 4; ++i)
#pragma unroll
        for (int jj = 0; jj < 4; ++jj) acc[i][jj] = zero4;

    for (int kt = 0; kt < K_ / 64; ++kt) {
        const int k0 = kt * 64;
#pragma unroll
        for (int p = 0; p < 4; ++p) {
            const int R0 = w * 32 + p * 8;
            const int r = R0 + lane3;
            const int ca = (pc ^ (r & 7)) * 8;     // swizzled logical chunk
            gld16(A  + (size_t)(m0 + r) * K_ + k0 + ca, As + R0 * 64);
            gld16(Bw + (size_t)(n0 + r) * K_ + k0 + ca, Bs + R0 * 64);
        }
        asm volatile("s_waitcnt vmcnt(0)" ::: "memory");
        __syncthreads();
#pragma unroll
        for (int kk = 0; kk < 2; ++kk) {
            bf16x8 af[4], bfr[4];
#pragma unroll
            for (int i = 0; i < 4; ++i) {
                const int rowa = wm * 64 + i * 16 + l15;
                const int rowb = wn * 64 + i * 16 + l15;
                const int ca = ((kk * 4 + quad) ^ ra7) * 8;
                af[i]  = *(const bf16x8*)(const void*)(&As[rowa * 64 + ca]);
                bfr[i] = *(const bf16x8*)(const void*)(&Bs[rowb * 64 + ca]);
            }
#pragma unroll
            for (int i = 0; i < 4; ++i)
#pragma unroll
                for (int jj = 0; jj < 4; ++jj)
                    acc[i][jj] = __builtin_amdgcn_mfma_f32_16x16x32_bf16(
                        af[i], bfr[jj], acc[i][jj], 0, 0, 0);
        }
        __syncthreads();   // LDS consumed; next kt may overwrite
    }

    // ---- epilogue (C/D layout: col=lane&15, row=quad*4+reg) ----
    // stage fp32 64 rows x 128 cols at a time (32 KB)
    float* Cf = (float*)smem;
    const int col4 = (tid & 31) * 4;
    float4 b4;
    if (EPI == 0) b4 = *(const float4*)(const void*)(bias + n0 + col4);
    else          b4 = *(const float4*)(const void*)(bias + n0 + col4);
#pragma unroll
    for (int half = 0; half < 2; ++half) {
        if (wm == half) {
#pragma unroll
            for (int i = 0; i < 4; ++i) {
                const int lrow0 = i * 16 + quad * 4;
#pragma unroll
                for (int jj = 0; jj < 4; ++jj) {
                    const int col = wn * 64 + jj * 16 + l15;
#pragma unroll
                    for (int r = 0; r < 4; ++r)
                        Cf[(lrow0 + r) * 128 + col] = acc[i][jj][r];
                }
            }
        }
        __syncthreads();
#pragma unroll
        for (int q = 0; q < 8; ++q) {
            const int lrow = q * 8 + (tid >> 5);
            const int grow = m0 + half * 64 + lrow;
            float4 v = *(const float4*)(const void*)(&Cf[lrow * 128 + col4]);
            if (EPI == 0) {
                if (tileN < 4) {
                    // (i,h) pairs -> 2 ig outputs
                    const float ig0 = sigm(v.x + b4.x) * fmaxf(v.y + b4.y, 0.f);
                    const float ig1 = sigm(v.z + b4.z) * fmaxf(v.w + b4.w, 0.f);
                    *(u32*)(void*)(Gout + (size_t)grow * G2_ + tileN * 64 + (col4 >> 1))
                        = pack2h(ig0, ig1);
                } else {
                    // pure f tile -> 4 f outputs
                    uint2 pk;
                    pk.x = pack2h(sigm(v.x + b4.x), sigm(v.y + b4.y));
                    pk.y = pack2h(sigm(v.z + b4.z), sigm(v.w + b4.w));
                    *(uint2*)(void*)(Gout + (size_t)grow * G2_ + 256 + (tileN - 4) * 128 + col4)
                        = pk;
                }
            } else {
                const u16* cp = cellbuf + (size_t)grow * K_ + 256 + n0 + col4;
                float4 o;
                o.x = sigm(v.x + b4.x) * bf2f(cp[0]);
                o.y = sigm(v.y + b4.y) * bf2f(cp[1]);
                o.z = sigm(v.z + b4.z) * bf2f(cp[2]);
                o.w = sigm(v.w + b4.w) * bf2f(cp[3]);
                *(float4*)(void*)(Out + (size_t)grow * N2_ + n0 + col4) = o;
            }
        }
        __syncthreads();
    }
}

// ---- scan phase 1: local recurrence over 64 steps; 4 outputs/thread ----
// g' is pre-activated fp16: [ig | f]. grid: B*H*8 blocks x 256 thr (4 chunks/blk)
__global__ __launch_bounds__(256) void scan_phase1(
    const u16* __restrict__ g2, float* __restrict__ cF, float* __restrict__ cC)
{
    const int blk = blockIdx.x;              // (b*8+h)*8 + chp
    const int chp = blk & 7, bh = blk >> 3;
    const int h = bh & 7, b = bh >> 3;
    const int t = threadIdx.x;
    const int ch = chp * 4 + (t >> 6);
    const int o = (t & 63) * 4;
    float F[4] = {1.f, 1.f, 1.f, 1.f};
    float c[4] = {0.f, 0.f, 0.f, 0.f};
    for (int i = 0; i < 64; ++i) {
        const int s = ch * 64 + i;
        const size_t m = ((size_t)(b * S_ + s)) * H_ + h;
        const u16* gp = g2 + m * G2_;
        const uint2 igp = *(const uint2*)(const void*)(gp + o);
        const uint2 fgp = *(const uint2*)(const void*)(gp + 256 + o);
        const float f0 = h2f((u16)fgp.x), f1 = h2f((u16)(fgp.x >> 16));
        const float f2 = h2f((u16)fgp.y), f3 = h2f((u16)(fgp.y >> 16));
        c[0] = f0 * c[0] + h2f((u16)igp.x);        F[0] *= f0;
        c[1] = f1 * c[1] + h2f((u16)(igp.x >> 16)); F[1] *= f1;
        c[2] = f2 * c[2] + h2f((u16)igp.y);        F[2] *= f2;
        c[3] = f3 * c[3] + h2f((u16)(igp.y >> 16)); F[3] *= f3;
    }
    const size_t idx = ((size_t)(bh * 32 + ch)) * 256 + o;
    *(float4*)(void*)(cF + idx) = make_float4(F[0], F[1], F[2], F[3]);
    *(float4*)(void*)(cC + idx) = make_float4(c[0], c[1], c[2], c[3]);
}

// ---- scan carry combine ----
__global__ __launch_bounds__(256) void scan_mid(
    const float* __restrict__ cF, const float* __restrict__ cC,
    const float* __restrict__ initcx, float* __restrict__ cin)
{
    const int bh = blockIdx.x;               // b*8 + h
    const int h = bh & 7;
    const int o = threadIdx.x;
    float c = initcx[h * 256 + o];
    for (int ch = 0; ch < 32; ++ch) {
        const size_t idx = ((size_t)(bh * 32 + ch)) * 256 + o;
        cin[idx] = c;
        c = cF[idx] * c + cC[idx];
    }
}

// ---- scan phase 2: replay; write cell bf16 into x2 cols [256,512) ----
__global__ __launch_bounds__(256) void scan_phase2(
    const u16* __restrict__ g2, const float* __restrict__ cin,
    u16* __restrict__ x2)
{
    const int blk = blockIdx.x;
    const int chp = blk & 7, bh = blk >> 3;
    const int h = bh & 7, b = bh >> 3;
    const int t = threadIdx.x;
    const int ch = chp * 4 + (t >> 6);
    const int o = (t & 63) * 4;
    const size_t idx = ((size_t)(bh * 32 + ch)) * 256 + o;
    float4 c4 = *(const float4*)(const void*)(cin + idx);
    float c[4] = {c4.x, c4.y, c4.z, c4.w};
    for (int i = 0; i < 64; ++i) {
        const int s = ch * 64 + i;
        const size_t m = ((size_t)(b * S_ + s)) * H_ + h;
        const u16* gp = g2 + m * G2_;
        const uint2 igp = *(const uint2*)(const void*)(gp + o);
        const uint2 fgp = *(const uint2*)(const void*)(gp + 256 + o);
        const float f0 = h2f((u16)fgp.x), f1 = h2f((u16)(fgp.x >> 16));
        const float f2 = h2f((u16)fgp.y), f3 = h2f((u16)(fgp.y >> 16));
        c[0] = f0 * c[0] + h2f((u16)igp.x);
        c[1] = f1 * c[1] + h2f((u16)(igp.x >> 16));
        c[2] = f2 * c[2] + h2f((u16)igp.y);
        c[3] = f3 * c[3] + h2f((u16)(igp.y >> 16));
        uint2 pk;
        pk.x = (u32)f2bf(c[0]) | ((u32)f2bf(c[1]) << 16);
        pk.y = (u32)f2bf(c[2]) | ((u32)f2bf(c[3]) << 16);
        *(uint2*)(void*)(x2 + m * K_ + 256 + o) = pk;
    }
}

extern "C" void kernel_launch(void* const* d_in, const int* in_sizes, int n_in,
                              void* d_out, int out_size, void* d_ws, size_t ws_size,
                              hipStream_t stream)
{
    const float* X      = (const float*)d_in[0];
    const float* Whid   = (const float*)d_in[1];
    const float* bhid   = (const float*)d_in[2];
    const float* Wog    = (const float*)d_in[3];
    const float* bog    = (const float*)d_in[4];
    const float* lnw    = (const float*)d_in[5];
    const float* lnb    = (const float*)d_in[6];
    const float* initcx = (const float*)d_in[7];
    float* out = (float*)d_out;

    char* ws = (char*)d_ws;
    u16* x2   = (u16*)(ws + OFF_X2);
    u16* g    = (u16*)(ws + OFF_G);
    u16* WhB  = (u16*)(ws + OFF_WH);
    u16* WoB  = (u16*)(ws + OFF_WO);
    float* aux = (float*)(ws + OFF_AUX);
    float* cF  = (float*)(ws + OFF_CF);
    float* cC  = (float*)(ws + OFF_CC);
    float* cin = (float*)(ws + OFF_CIN);
    float* br  = (float*)(ws + OFF_BR);

    wconv_kernel<<<(N1_*K_ + 255) / 256, 256, 0, stream>>>(Whid, bhid, Wog, WhB, WoB, br);
    csum_phase1<<<B_ * CSCH, 256, 0, stream>>>(X, aux);
    csum_mid<<<64, 256, 0, stream>>>(aux);
    csum_phase2<<<B_ * CSCH, 256, 0, stream>>>(X, aux, lnw, lnb, x2);
    gemm_kernel<N1_, 0><<<(M_ / 128) * (N1_ / 128), 256, 0, stream>>>(
        x2, WhB, g, br, nullptr, nullptr);
    scan_phase1<<<B_ * H_ * 8, 256, 0, stream>>>(g, cF, cC);
    scan_mid<<<B_ * H_, 256, 0, stream>>>(cF, cC, initcx, cin);
    scan_phase2<<<B_ * H_ * 8, 256, 0, stream>>>(g, cin, x2);
    gemm_kernel<N2_, 1><<<(M_ / 128) * (N2_ / 128), 256, 0, stream>>>(
        x2, WoB, nullptr, bog, x2, out);
}

// Round 2
// 623.398 us; speedup vs baseline: 1.0303x; 1.0266x over previous
//
#include <hip/hip_runtime.h>

typedef unsigned short u16;
typedef unsigned int u32;

typedef __attribute__((ext_vector_type(8))) short bf16x8;
typedef __attribute__((ext_vector_type(4))) float f32x4;

#define B_ 8
#define S_ 2048
#define H_ 8
#define ID_ 256
#define OD_ 256
#define K_ 512
#define M_ (B_*S_*H_)   /* 131072 */
#define N1_ 768
#define N2_ 256
#define G2_ 512          /* activated-gate tensor width: [ig(256) | f(256)] fp16 */

#define CSCH 64            /* cumsum chunks over S */
#define CSST (S_/CSCH)     /* 32 steps per chunk */

// ---- workspace layout (bytes) ----
#define OFF_X2   (0ull)
#define SZ_X2    ((unsigned long long)M_*K_*2)        /* 134,217,728 */
#define OFF_G    (OFF_X2 + SZ_X2)
#define SZ_G     ((unsigned long long)M_*G2_*2)       /* 134,217,728 */
#define OFF_WH   (OFF_G + SZ_G)
#define SZ_WH    ((unsigned long long)N1_*K_*2)
#define OFF_WO   (OFF_WH + SZ_WH)
#define SZ_WO    ((unsigned long long)N2_*K_*2)
#define OFF_AUX  (OFF_WO + SZ_WO)
#define SZ_AUX   ((unsigned long long)B_*CSCH*2048*4)
#define OFF_CF   (OFF_AUX + SZ_AUX)
#define SZ_CARR  ((unsigned long long)B_*H_*32*256*4)
#define OFF_CC   (OFF_CF + SZ_CARR)
#define OFF_CIN  (OFF_CC + SZ_CARR)

__device__ __forceinline__ u16 f2bf(float f) {
    union { float f; u32 u; } v; v.f = f;
    u32 u = v.u;
    u += 0x7fffu + ((u >> 16) & 1u);   // round-to-nearest-even
    return (u16)(u >> 16);
}
__device__ __forceinline__ float bf2f(u16 h) {
    union { u32 u; float f; } v; v.u = ((u32)h) << 16;
    return v.f;
}
__device__ __forceinline__ u32 pack2h(float a, float b) {
    union { _Float16 h; u16 u; } x, y;
    x.h = (_Float16)a; y.h = (_Float16)b;
    return (u32)x.u | ((u32)y.u << 16);
}
__device__ __forceinline__ float h2f(u16 u) {
    union { u16 u; _Float16 h; } v; v.u = u;
    return (float)v.h;
}
__device__ __forceinline__ float sigm(float x) {
    return 1.0f / (1.0f + __expf(-x));
}

// async 16B global->LDS DMA. LDS dest = wave-uniform base + lane*16.
__device__ __forceinline__ void gld16(const void* g, void* l) {
    __builtin_amdgcn_global_load_lds(
        (const __attribute__((address_space(1))) void*)g,
        (__attribute__((address_space(3))) void*)l, 16, 0, 0);
}

// W_hid row permutation.
// Pair tiles t=0..3 (n<512): in-tile col c: wn=c>>6, jj=(c&63)>>4, l=c&15
//   o = t*64 + wn*32 + (jj&1)*16 + l
//   jj in {0,1} -> igate row o ; jj in {2,3} -> hidden row 512+o
//   => per lane: ig_o = sig(acc[jj]) * relu(acc[jj+2])  (same lane, in-register)
// F tiles t=4,5: o = (t-4)*128 + c -> fgate row 256+o
__device__ __forceinline__ int whid_src_row(int n) {
    const int t = n >> 7, c = n & 127;
    if (t < 4) {
        const int wn = (c >> 6) & 1, jj = (c & 63) >> 4, l = c & 15;
        const int o = t * 64 + wn * 32 + (jj & 1) * 16 + l;
        return (jj < 2) ? o : (512 + o);
    }
    return 256 + (t - 4) * 128 + c;
}

// ---- 0: weights fp32 -> bf16 (W_hid rows permuted) ----
__global__ __launch_bounds__(256) void wconv_kernel(
    const float* __restrict__ Whid, const float* __restrict__ Wog,
    u16* __restrict__ WhB, u16* __restrict__ WoB)
{
    int idx = blockIdx.x * 256 + threadIdx.x;
    if (idx < N1_*K_) {
        const int n = idx >> 9, k = idx & 511;
        WhB[idx] = f2bf(Whid[(size_t)whid_src_row(n) * K_ + k]);
    }
    if (idx < N2_*K_) WoB[idx] = f2bf(Wog[idx]);
}

// ---- 1: cumsum phase 1 — per-(b,chunk) local totals over CSST s-steps ----
__global__ __launch_bounds__(256) void csum_phase1(
    const float* __restrict__ X, float* __restrict__ aux)
{
    const int bch = blockIdx.x;          // b*CSCH + ch
    const int b = bch / CSCH, ch = bch % CSCH;
    const int t = threadIdx.x;
    float acc[8];
#pragma unroll
    for (int h = 0; h < 8; ++h) acc[h] = 0.f;
    for (int i = 0; i < CSST; ++i) {
        const int s = ch * CSST + i;
        const float* xp = X + ((size_t)(b * S_ + s)) * 2048 + t;
#pragma unroll
        for (int h = 0; h < 8; ++h) acc[h] += xp[h * 256];
    }
    float* ap = aux + (size_t)bch * 2048 + t;
#pragma unroll
    for (int h = 0; h < 8; ++h) ap[h * 256] = acc[h];
}

// ---- 2: cumsum carry — exclusive prefix over CSCH chunks, in place ----
__global__ __launch_bounds__(256) void csum_mid(float* __restrict__ aux)
{
    const int idx = blockIdx.x * 256 + threadIdx.x;
    const int b = idx >> 11, c = idx & 2047;
    float run = 0.f;
    for (int ch = 0; ch < CSCH; ++ch) {
        float* p = aux + ((size_t)(b * CSCH + ch)) * 2048 + c;
        float v = *p; *p = run; run += v;
    }
}

// ---- 3: cumsum phase 2 — replay + LayerNorm + pack x2 bf16 ----
__global__ __launch_bounds__(256) void csum_phase2(
    const float* __restrict__ X, const float* __restrict__ aux,
    const float* __restrict__ lnw, const float* __restrict__ lnb,
    u16* __restrict__ x2)
{
    const int bch = blockIdx.x;
    const int b = bch / CSCH, ch = bch % CSCH;
    const int t = threadIdx.x;
    float c[8], wv[8], bv[8];
#pragma unroll
    for (int h = 0; h < 8; ++h) {
        c[h]  = aux[(size_t)bch * 2048 + h * 256 + t];
        wv[h] = lnw[h * 256 + t];
        bv[h] = lnb[h * 256 + t];
    }
    __shared__ float red[2][4];
    for (int i = 0; i < CSST; ++i) {
        const int s = ch * CSST + i;
        const float* xp = X + ((size_t)(b * S_ + s)) * 2048 + t;
        float xa[8];
#pragma unroll
        for (int h = 0; h < 8; ++h) { xa[h] = xp[h * 256]; c[h] += xa[h]; }
        float sx = 0.f, sq = 0.f;
#pragma unroll
        for (int h = 0; h < 8; ++h) { sx += c[h]; sq += c[h] * c[h]; }
#pragma unroll
        for (int off = 32; off >= 1; off >>= 1) {
            sx += __shfl_down(sx, (unsigned)off);
            sq += __shfl_down(sq, (unsigned)off);
        }
        const int wid = t >> 6;
        if ((t & 63) == 0) { red[0][wid] = sx; red[1][wid] = sq; }
        __syncthreads();
        const float tsx = red[0][0] + red[0][1] + red[0][2] + red[0][3];
        const float tsq = red[1][0] + red[1][1] + red[1][2] + red[1][3];
        __syncthreads();
        const float mean = tsx * (1.f / 2048.f);
        const float var  = tsq * (1.f / 2048.f) - mean * mean;
        const float rstd = rsqrtf(var + 1e-6f);
        const size_t mrow = ((size_t)(b * S_ + s)) * H_;
#pragma unroll
        for (int h = 0; h < 8; ++h) {
            u16* row = x2 + (mrow + h) * (size_t)K_;
            row[t]       = f2bf(xa[h]);
            row[256 + t] = f2bf((c[h] - mean) * rstd * wv[h] + bv[h]);
        }
    }
}

// ---- GEMM: C[m,n] = sum_k A[m,k] * W[n,k], A/W bf16 row-major (ld=512) ----
// 128x128 tile, BK=64, 4 waves (2x2) x 64x64 each via 4x4 mfma_16x16x32_bf16.
// EPI==0 (GATE): in-register activations from fp32 acc, write fp16 g'.
//   g' row layout (u16[512]): [0,256) ig slots, [256,512) f slots.
//   u32 slot q holds (val_{o'}, val_{o'+16}) with o' = (q>>4)*32 + (q&15).
//   bias = original bhid (unpermuted, 768 floats).
// EPI==1 (OG): fp32 out with sigmoid(x+b)*cell (staged fp32 epilogue).
template<int N, int EPI>
__global__ __launch_bounds__(256) void gemm_kernel(
    const u16* __restrict__ A, const u16* __restrict__ Bw,
    u16* __restrict__ Gout, const float* __restrict__ bias,
    const u16* __restrict__ cellbuf, float* __restrict__ Out)
{
    constexpr int NT = N / 128;
    const int blk = blockIdx.x;
    const int xcd = blk & 7;
    const int j = blk >> 3;
    const int tileN = j % NT;
    const int tileM = (j / NT) * 8 + xcd;
    const int m0 = tileM * 128, n0 = tileN * 128;
    const int tid = threadIdx.x;
    const int lane = tid & 63;
    const int w = tid >> 6, wm = w & 1, wn = w >> 1;
    const int l15 = lane & 15, quad = lane >> 4;

    __shared__ __align__(16) u16 smem[2 * 128 * 64];   // 32 KB
    u16* As = smem;
    u16* Bs = smem + 128 * 64;

    const int lane3 = lane >> 3;   // row-within-8-group
    const int pc = lane & 7;       // physical 16B chunk
    const int ra7 = l15 & 7;       // row&7 for fragment reads

    f32x4 acc[4][4];
    const f32x4 zero4 = {0.f, 0.f, 0.f, 0.f};
#pragma unroll
    for (int i = 0; i < 4; ++i)
#pragma unroll
        for (int jj = 0; jj < 4; ++jj) acc[i][jj] = zero4;

    for (int kt = 0; kt < K_ / 64; ++kt) {
        const int k0 = kt * 64;
#pragma unroll
        for (int p = 0; p < 4; ++p) {
            const int R0 = w * 32 + p * 8;
            const int r = R0 + lane3;
            const int ca = (pc ^ (r & 7)) * 8;     // swizzled logical chunk
            gld16(A  + (size_t)(m0 + r) * K_ + k0 + ca, As + R0 * 64);
            gld16(Bw + (size_t)(n0 + r) * K_ + k0 + ca, Bs + R0 * 64);
        }
        asm volatile("s_waitcnt vmcnt(0)" ::: "memory");
        __syncthreads();
#pragma unroll
        for (int kk = 0; kk < 2; ++kk) {
            bf16x8 af[4], bfr[4];
#pragma unroll
            for (int i = 0; i < 4; ++i) {
                const int rowa = wm * 64 + i * 16 + l15;
                const int rowb = wn * 64 + i * 16 + l15;
                const int ca = ((kk * 4 + quad) ^ ra7) * 8;
                af[i]  = *(const bf16x8*)(const void*)(&As[rowa * 64 + ca]);
                bfr[i] = *(const bf16x8*)(const void*)(&Bs[rowb * 64 + ca]);
            }
#pragma unroll
            for (int i = 0; i < 4; ++i)
#pragma unroll
                for (int jj = 0; jj < 4; ++jj)
                    acc[i][jj] = __builtin_amdgcn_mfma_f32_16x16x32_bf16(
                        af[i], bfr[jj], acc[i][jj], 0, 0, 0);
        }
        __syncthreads();   // LDS consumed; next kt may overwrite
    }

    // ---- epilogue (C/D layout: col=lane&15, row=quad*4+reg) ----
    if (EPI == 0) {
        // fully in-register; no LDS, no barriers
        const int m_base = m0 + wm * 64 + quad * 4;
        if (tileN < 4) {
            const int o0 = tileN * 64 + wn * 32 + l15;
            const float bI0 = bias[o0],        bI1 = bias[o0 + 16];
            const float bH0 = bias[512 + o0],  bH1 = bias[512 + o0 + 16];
            const int q = (tileN * 2 + wn) * 16 + l15;   // u32 slot
#pragma unroll
            for (int i = 0; i < 4; ++i) {
#pragma unroll
                for (int r = 0; r < 4; ++r) {
                    const int m = m_base + i * 16 + r;
                    const float ig0 = sigm(acc[i][0][r] + bI0) * fmaxf(acc[i][2][r] + bH0, 0.f);
                    const float ig1 = sigm(acc[i][1][r] + bI1) * fmaxf(acc[i][3][r] + bH1, 0.f);
                    *(u32*)(void*)(Gout + (size_t)m * G2_ + 2 * q) = pack2h(ig0, ig1);
                }
            }
        } else {
            const int o0 = (tileN - 4) * 128 + wn * 64 + l15;
            const float bF0 = bias[256 + o0],      bF1 = bias[256 + o0 + 16];
            const float bF2 = bias[256 + o0 + 32], bF3 = bias[256 + o0 + 48];
            const int qA = ((tileN - 4) * 4 + wn * 2) * 16 + l15;   // (o0, o0+16)
            const int qB = qA + 16;                                  // (o0+32, o0+48)
#pragma unroll
            for (int i = 0; i < 4; ++i) {
#pragma unroll
                for (int r = 0; r < 4; ++r) {
                    const int m = m_base + i * 16 + r;
                    u16* row = Gout + (size_t)m * G2_ + 256;
                    *(u32*)(void*)(row + 2 * qA) =
                        pack2h(sigm(acc[i][0][r] + bF0), sigm(acc[i][1][r] + bF1));
                    *(u32*)(void*)(row + 2 * qB) =
                        pack2h(sigm(acc[i][2][r] + bF2), sigm(acc[i][3][r] + bF3));
                }
            }
        }
    } else {
        // fp32 out with sigmoid(x+b)*cell; stage 64 rows at a time
        float* Cf = (float*)smem;           // 64 x 128 fp32 = 32 KB
        const int col4 = (tid & 31) * 4;
        float4 b4 = *(const float4*)(const void*)(bias + n0 + col4);
#pragma unroll
        for (int half = 0; half < 2; ++half) {
            if (wm == half) {
#pragma unroll
                for (int i = 0; i < 4; ++i) {
                    const int lrow0 = i * 16 + quad * 4;
#pragma unroll
                    for (int jj = 0; jj < 4; ++jj) {
                        const int col = wn * 64 + jj * 16 + l15;
#pragma unroll
                        for (int r = 0; r < 4; ++r)
                            Cf[(lrow0 + r) * 128 + col] = acc[i][jj][r];
                    }
                }
            }
            __syncthreads();
#pragma unroll
            for (int q = 0; q < 8; ++q) {
                const int lrow = q * 8 + (tid >> 5);
                const int grow = m0 + half * 64 + lrow;
                float4 v = *(const float4*)(const void*)(&Cf[lrow * 128 + col4]);
                const u16* cp = cellbuf + (size_t)grow * K_ + 256 + n0 + col4;
                float4 o;
                o.x = sigm(v.x + b4.x) * bf2f(cp[0]);
                o.y = sigm(v.y + b4.y) * bf2f(cp[1]);
                o.z = sigm(v.z + b4.z) * bf2f(cp[2]);
                o.w = sigm(v.w + b4.w) * bf2f(cp[3]);
                *(float4*)(void*)(Out + (size_t)grow * N2_ + n0 + col4) = o;
            }
            __syncthreads();
        }
    }
}

// ---- scan phase 1: local recurrence over 64 steps; 4 values/thread ----
// g' is pre-activated fp16 in slot order; recurrence is order-agnostic, so
// carries (cF/cC/cin) stay in storage order. grid: B*H*8 blocks x 256 thr.
__global__ __launch_bounds__(256) void scan_phase1(
    const u16* __restrict__ g2, float* __restrict__ cF, float* __restrict__ cC)
{
    const int blk = blockIdx.x;              // (b*8+h)*8 + chp
    const int chp = blk & 7, bh = blk >> 3;
    const int h = bh & 7, b = bh >> 3;
    const int t = threadIdx.x;
    const int ch = chp * 4 + (t >> 6);
    const int o = (t & 63) * 4;              // storage u16 offset
    float F[4] = {1.f, 1.f, 1.f, 1.f};
    float c[4] = {0.f, 0.f, 0.f, 0.f};
    for (int i = 0; i < 64; ++i) {
        const int s = ch * 64 + i;
        const size_t m = ((size_t)(b * S_ + s)) * H_ + h;
        const u16* gp = g2 + m * G2_;
        const uint2 igp = *(const uint2*)(const void*)(gp + o);
        const uint2 fgp = *(const uint2*)(const void*)(gp + 256 + o);
        const float f0 = h2f((u16)fgp.x), f1 = h2f((u16)(fgp.x >> 16));
        const float f2 = h2f((u16)fgp.y), f3 = h2f((u16)(fgp.y >> 16));
        c[0] = f0 * c[0] + h2f((u16)igp.x);         F[0] *= f0;
        c[1] = f1 * c[1] + h2f((u16)(igp.x >> 16)); F[1] *= f1;
        c[2] = f2 * c[2] + h2f((u16)igp.y);         F[2] *= f2;
        c[3] = f3 * c[3] + h2f((u16)(igp.y >> 16)); F[3] *= f3;
    }
    const size_t idx = ((size_t)(bh * 32 + ch)) * 256 + o;
    *(float4*)(void*)(cF + idx) = make_float4(F[0], F[1], F[2], F[3]);
    *(float4*)(void*)(cC + idx) = make_float4(c[0], c[1], c[2], c[3]);
}

// ---- scan carry combine (storage order; initcx needs real o) ----
__global__ __launch_bounds__(256) void scan_mid(
    const float* __restrict__ cF, const float* __restrict__ cC,
    const float* __restrict__ initcx, float* __restrict__ cin)
{
    const int bh = blockIdx.x;               // b*8 + h
    const int h = bh & 7;
    const int a = threadIdx.x;               // storage position
    const int q = a >> 1, hfl = a & 1;
    const int ro = ((q >> 4) << 5) + (q & 15) + (hfl << 4);  // real o
    float c = initcx[h * 256 + ro];
    for (int ch = 0; ch < 32; ++ch) {
        const size_t idx = ((size_t)(bh * 32 + ch)) * 256 + a;
        cin[idx] = c;
        c = cF[idx] * c + cC[idx];
    }
}

// ---- scan phase 2: replay; write cell bf16 (real o order) into x2 ----
__global__ __launch_bounds__(256) void scan_phase2(
    const u16* __restrict__ g2, const float* __restrict__ cin,
    u16* __restrict__ x2)
{
    const int blk = blockIdx.x;
    const int chp = blk & 7, bh = blk >> 3;
    const int h = bh & 7, b = bh >> 3;
    const int t = threadIdx.x;
    const int ch = chp * 4 + (t >> 6);
    const int z = t & 63;
    const int o = z * 4;                     // storage u16 offset
    // storage positions o..o+3 map to real o's: oA, oA+16, oA+1, oA+17
    const int oA = ((z >> 3) << 5) + ((z & 7) << 1);
    const size_t idx = ((size_t)(bh * 32 + ch)) * 256 + o;
    float4 c4 = *(const float4*)(const void*)(cin + idx);
    float c[4] = {c4.x, c4.y, c4.z, c4.w};
    for (int i = 0; i < 64; ++i) {
        const int s = ch * 64 + i;
        const size_t m = ((size_t)(b * S_ + s)) * H_ + h;
        const u16* gp = g2 + m * G2_;
        const uint2 igp = *(const uint2*)(const void*)(gp + o);
        const uint2 fgp = *(const uint2*)(const void*)(gp + 256 + o);
        const float f0 = h2f((u16)fgp.x), f1 = h2f((u16)(fgp.x >> 16));
        const float f2 = h2f((u16)fgp.y), f3 = h2f((u16)(fgp.y >> 16));
        c[0] = f0 * c[0] + h2f((u16)igp.x);
        c[1] = f1 * c[1] + h2f((u16)(igp.x >> 16));
        c[2] = f2 * c[2] + h2f((u16)igp.y);
        c[3] = f3 * c[3] + h2f((u16)(igp.y >> 16));
        u16* xr = x2 + m * K_ + 256;
        const u32 pkA = (u32)f2bf(c[0]) | ((u32)f2bf(c[2]) << 16);  // cols oA, oA+1
        const u32 pkB = (u32)f2bf(c[1]) | ((u32)f2bf(c[3]) << 16);  // cols oA+16, oA+17
        *(u32*)(void*)(xr + oA)      = pkA;
        *(u32*)(void*)(xr + oA + 16) = pkB;
    }
}

extern "C" void kernel_launch(void* const* d_in, const int* in_sizes, int n_in,
                              void* d_out, int out_size, void* d_ws, size_t ws_size,
                              hipStream_t stream)
{
    const float* X      = (const float*)d_in[0];
    const float* Whid   = (const float*)d_in[1];
    const float* bhid   = (const float*)d_in[2];
    const float* Wog    = (const float*)d_in[3];
    const float* bog    = (const float*)d_in[4];
    const float* lnw    = (const float*)d_in[5];
    const float* lnb    = (const float*)d_in[6];
    const float* initcx = (const float*)d_in[7];
    float* out = (float*)d_out;

    char* ws = (char*)d_ws;
    u16* x2   = (u16*)(ws + OFF_X2);
    u16* g    = (u16*)(ws + OFF_G);
    u16* WhB  = (u16*)(ws + OFF_WH);
    u16* WoB  = (u16*)(ws + OFF_WO);
    float* aux = (float*)(ws + OFF_AUX);
    float* cF  = (float*)(ws + OFF_CF);
    float* cC  = (float*)(ws + OFF_CC);
    float* cin = (float*)(ws + OFF_CIN);

    wconv_kernel<<<(N1_*K_ + 255) / 256, 256, 0, stream>>>(Whid, Wog, WhB, WoB);
    csum_phase1<<<B_ * CSCH, 256, 0, stream>>>(X, aux);
    csum_mid<<<64, 256, 0, stream>>>(aux);
    csum_phase2<<<B_ * CSCH, 256, 0, stream>>>(X, aux, lnw, lnb, x2);
    gemm_kernel<N1_, 0><<<(M_ / 128) * (N1_ / 128), 256, 0, stream>>>(
        x2, WhB, g, bhid, nullptr, nullptr);
    scan_phase1<<<B_ * H_ * 8, 256, 0, stream>>>(g, cF, cC);
    scan_mid<<<B_ * H_, 256, 0, stream>>>(cF, cC, initcx, cin);
    scan_phase2<<<B_ * H_ * 8, 256, 0, stream>>>(g, cin, x2);
    gemm_kernel<N2_, 1><<<(M_ / 128) * (N2_ / 128), 256, 0, stream>>>(
        x2, WoB, nullptr, bog, x2, out);
}

// Round 3
// 562.336 us; speedup vs baseline: 1.1421x; 1.1086x over previous
//
#include <hip/hip_runtime.h>

typedef unsigned short u16;
typedef unsigned int u32;

typedef __attribute__((ext_vector_type(8))) short bf16x8;
typedef __attribute__((ext_vector_type(4))) float f32x4;

#define B_ 8
#define S_ 2048
#define H_ 8
#define ID_ 256
#define OD_ 256
#define K_ 512
#define M_ (B_*S_*H_)   /* 131072 */
#define N1_ 768
#define N2_ 256
#define G2_ 512          /* activated-gate tensor width: [ig(256) | f(256)] fp16 */

#define CSCH 64            /* cumsum chunks over S */
#define CSST (S_/CSCH)     /* 32 steps per chunk */

// ---- workspace layout (bytes) ----
#define OFF_X2   (0ull)
#define SZ_X2    ((unsigned long long)M_*K_*2)        /* 134,217,728 */
#define OFF_G    (OFF_X2 + SZ_X2)
#define SZ_G     ((unsigned long long)M_*G2_*2)       /* 134,217,728 */
#define OFF_WH   (OFF_G + SZ_G)
#define SZ_WH    ((unsigned long long)N1_*K_*2)
#define OFF_WO   (OFF_WH + SZ_WH)
#define SZ_WO    ((unsigned long long)N2_*K_*2)
#define OFF_AUX  (OFF_WO + SZ_WO)
#define SZ_AUX   ((unsigned long long)B_*CSCH*2048*4)
#define OFF_CF   (OFF_AUX + SZ_AUX)
#define SZ_CARR  ((unsigned long long)B_*H_*32*256*4)
#define OFF_CC   (OFF_CF + SZ_CARR)
#define OFF_CIN  (OFF_CC + SZ_CARR)

__device__ __forceinline__ u16 f2bf(float f) {
    union { float f; u32 u; } v; v.f = f;
    u32 u = v.u;
    u += 0x7fffu + ((u >> 16) & 1u);   // round-to-nearest-even
    return (u16)(u >> 16);
}
__device__ __forceinline__ float bf2f(u16 h) {
    union { u32 u; float f; } v; v.u = ((u32)h) << 16;
    return v.f;
}
__device__ __forceinline__ u32 pack2h(float a, float b) {
    union { _Float16 h; u16 u; } x, y;
    x.h = (_Float16)a; y.h = (_Float16)b;
    return (u32)x.u | ((u32)y.u << 16);
}
__device__ __forceinline__ float h2f(u16 u) {
    union { u16 u; _Float16 h; } v; v.u = u;
    return (float)v.h;
}
__device__ __forceinline__ float sigm(float x) {
    return 1.0f / (1.0f + __expf(-x));
}

// async 16B global->LDS DMA. LDS dest = wave-uniform base + lane*16.
__device__ __forceinline__ void gld16(const void* g, void* l) {
    __builtin_amdgcn_global_load_lds(
        (const __attribute__((address_space(1))) void*)g,
        (__attribute__((address_space(3))) void*)l, 16, 0, 0);
}

// W_hid row permutation (256-wide tiles, 8 waves of 64 cols).
// Pair tiles t=0,1 (n<512): c=n&255, wn=c>>6, jj=(c>>4)&3, l=c&15
//   o = t*128 + wn*32 + (jj&1)*16 + l
//   jj in {0,1} -> igate row o ; jj in {2,3} -> hidden row 512+o
//   => per lane: ig_o = sig(acc[jj]) * relu(acc[jj+2])  (same lane, in-register)
// F tile t=2: o = n-512 -> fgate row 256+o (natural)
__device__ __forceinline__ int whid_src_row(int n) {
    const int t = n >> 8, c = n & 255;
    if (t < 2) {
        const int wn = c >> 6, jj = (c >> 4) & 3, l = c & 15;
        const int o = t * 128 + wn * 32 + (jj & 1) * 16 + l;
        return (jj < 2) ? o : (512 + o);
    }
    return 256 + (n - 512);
}

// ---- 0: weights fp32 -> bf16 (W_hid rows permuted) ----
__global__ __launch_bounds__(256) void wconv_kernel(
    const float* __restrict__ Whid, const float* __restrict__ Wog,
    u16* __restrict__ WhB, u16* __restrict__ WoB)
{
    int idx = blockIdx.x * 256 + threadIdx.x;
    if (idx < N1_*K_) {
        const int n = idx >> 9, k = idx & 511;
        WhB[idx] = f2bf(Whid[(size_t)whid_src_row(n) * K_ + k]);
    }
    if (idx < N2_*K_) WoB[idx] = f2bf(Wog[idx]);
}

// ---- 1: cumsum phase 1 — per-(b,chunk) local totals over CSST s-steps ----
__global__ __launch_bounds__(256) void csum_phase1(
    const float* __restrict__ X, float* __restrict__ aux)
{
    const int bch = blockIdx.x;          // b*CSCH + ch
    const int b = bch / CSCH, ch = bch % CSCH;
    const int t = threadIdx.x;
    float acc[8];
#pragma unroll
    for (int h = 0; h < 8; ++h) acc[h] = 0.f;
    for (int i = 0; i < CSST; ++i) {
        const int s = ch * CSST + i;
        const float* xp = X + ((size_t)(b * S_ + s)) * 2048 + t;
#pragma unroll
        for (int h = 0; h < 8; ++h) acc[h] += xp[h * 256];
    }
    float* ap = aux + (size_t)bch * 2048 + t;
#pragma unroll
    for (int h = 0; h < 8; ++h) ap[h * 256] = acc[h];
}

// ---- 2: cumsum carry — exclusive prefix over CSCH chunks, in place ----
__global__ __launch_bounds__(256) void csum_mid(float* __restrict__ aux)
{
    const int idx = blockIdx.x * 256 + threadIdx.x;
    const int b = idx >> 11, c = idx & 2047;
    float run = 0.f;
    for (int ch = 0; ch < CSCH; ++ch) {
        float* p = aux + ((size_t)(b * CSCH + ch)) * 2048 + c;
        float v = *p; *p = run; run += v;
    }
}

// ---- 3: cumsum phase 2 — replay + LayerNorm + pack x2 bf16 ----
__global__ __launch_bounds__(256) void csum_phase2(
    const float* __restrict__ X, const float* __restrict__ aux,
    const float* __restrict__ lnw, const float* __restrict__ lnb,
    u16* __restrict__ x2)
{
    const int bch = blockIdx.x;
    const int b = bch / CSCH, ch = bch % CSCH;
    const int t = threadIdx.x;
    float c[8], wv[8], bv[8];
#pragma unroll
    for (int h = 0; h < 8; ++h) {
        c[h]  = aux[(size_t)bch * 2048 + h * 256 + t];
        wv[h] = lnw[h * 256 + t];
        bv[h] = lnb[h * 256 + t];
    }
    __shared__ float red[2][4];
    for (int i = 0; i < CSST; ++i) {
        const int s = ch * CSST + i;
        const float* xp = X + ((size_t)(b * S_ + s)) * 2048 + t;
        float xa[8];
#pragma unroll
        for (int h = 0; h < 8; ++h) { xa[h] = xp[h * 256]; c[h] += xa[h]; }
        float sx = 0.f, sq = 0.f;
#pragma unroll
        for (int h = 0; h < 8; ++h) { sx += c[h]; sq += c[h] * c[h]; }
#pragma unroll
        for (int off = 32; off >= 1; off >>= 1) {
            sx += __shfl_down(sx, (unsigned)off);
            sq += __shfl_down(sq, (unsigned)off);
        }
        const int wid = t >> 6;
        if ((t & 63) == 0) { red[0][wid] = sx; red[1][wid] = sq; }
        __syncthreads();
        const float tsx = red[0][0] + red[0][1] + red[0][2] + red[0][3];
        const float tsq = red[1][0] + red[1][1] + red[1][2] + red[1][3];
        __syncthreads();
        const float mean = tsx * (1.f / 2048.f);
        const float var  = tsq * (1.f / 2048.f) - mean * mean;
        const float rstd = rsqrtf(var + 1e-6f);
        const size_t mrow = ((size_t)(b * S_ + s)) * H_;
#pragma unroll
        for (int h = 0; h < 8; ++h) {
            u16* row = x2 + (mrow + h) * (size_t)K_;
            row[t]       = f2bf(xa[h]);
            row[256 + t] = f2bf((c[h] - mean) * rstd * wv[h] + bv[h]);
        }
    }
}

// ---- GEMM: C[m,n] = sum_k A[m,k] * W[n,k], A/W bf16 row-major (ld=512) ----
// 256x256 tile, BK=32, 512 thr = 8 waves (2M x 4N), 128x64 out per wave,
// acc[8][4] via mfma_16x16x32_bf16.
// Deep pipeline: 4-buffer LDS ring (128 KiB), depth-3 prefetch with
// global_load_lds; counted s_waitcnt vmcnt(8) (never 0 mid-loop) + RAW
// s_barrier via asm (avoids hipcc's implicit vmcnt(0) drain at barriers).
// LDS rows are 64B (32 bf16); conflict swizzle: phys 16B chunk = c ^ ((row>>1)&3),
// applied on the GLOBAL source side for staging (gld16 dest must be linear)
// and on the read side for ds_read_b128 — conflict-free per 8-lane group.
// EPI==0 (GATE): in-register activations, write fp16 g' slots (see wconv map).
// EPI==1 (OG): in-register fp32 out = sigmoid(x+b)*cell.
template<int N, int EPI>
__global__ __launch_bounds__(512, 2) void gemm_kernel(
    const u16* __restrict__ A, const u16* __restrict__ Bw,
    u16* __restrict__ Gout, const float* __restrict__ bias,
    const u16* __restrict__ cellbuf, float* __restrict__ Out)
{
    constexpr int NT = N / 256;
    constexpr int KT = K_ / 32;     // 16 K-tiles
    const int blk = blockIdx.x;
    const int xcd = blk & 7;
    const int j = blk >> 3;
    const int tileN = j % NT;
    const int tileM = (j / NT) * 8 + xcd;
    const int m0 = tileM * 256, n0 = tileN * 256;
    const int tid = threadIdx.x;
    const int lane = tid & 63;
    const int w = tid >> 6;                 // wave 0..7
    const int wm = w >> 2, wn = w & 3;      // 2 x 4
    const int l15 = lane & 15, quad = lane >> 4;

    // 4 ring buffers x (A 256x32 + B 256x32) bf16 = 4 x 32 KB = 128 KB
    __shared__ __align__(16) u16 smem[4 * 16384];

    // --- staging geometry (per thread: 2 A-loads + 2 B-loads per K-tile) ---
    const int srow   = lane >> 2;                                  // 0..15
    const int schunk = ((lane & 3) ^ ((lane >> 3) & 3)) * 8;       // swizzled src col
    const u16* gA0 = A  + (size_t)(m0 + w * 32      + srow) * K_ + schunk;
    const u16* gA1 = A  + (size_t)(m0 + w * 32 + 16 + srow) * K_ + schunk;
    const u16* gB0 = Bw + (size_t)(n0 + w * 32      + srow) * K_ + schunk;
    const u16* gB1 = Bw + (size_t)(n0 + w * 32 + 16 + srow) * K_ + schunk;

    auto STAGE = [&](int bufb, int kt) {
        u16* sb = smem + bufb * 16384;
        gld16(gA0 + kt * 32, sb + (w * 32) * 32);
        gld16(gA1 + kt * 32, sb + (w * 32 + 16) * 32);
        gld16(gB0 + kt * 32, sb + 8192 + (w * 32) * 32);
        gld16(gB1 + kt * 32, sb + 8192 + (w * 32 + 16) * 32);
    };

    // --- fragment read geometry ---
    const int swz  = (quad ^ ((l15 >> 1) & 3)) * 8;                // swizzled chunk
    const int aoff = (wm * 128 + l15) * 32 + swz;                  // + mi*512
    const int boff = 8192 + (wn * 64 + l15) * 32 + swz;            // + jj*512

    f32x4 acc[8][4];
    const f32x4 zero4 = {0.f, 0.f, 0.f, 0.f};
#pragma unroll
    for (int mi = 0; mi < 8; ++mi)
#pragma unroll
        for (int jj = 0; jj < 4; ++jj) acc[mi][jj] = zero4;

    // prologue: stage tiles 0,1,2; wait tile 0 (8 = tiles 1,2 still in flight)
    STAGE(0, 0); STAGE(1, 1); STAGE(2, 2);
    asm volatile("s_waitcnt vmcnt(8)\n\ts_barrier" ::: "memory");

#pragma unroll
    for (int kt = 0; kt < KT; ++kt) {
        const int cur = kt & 3;
        if (kt + 3 < KT) STAGE((kt + 3) & 3, kt + 3);
        const u16* sb = smem + cur * 16384;
        bf16x8 af[8], bfr[4];
#pragma unroll
        for (int mi = 0; mi < 8; ++mi)
            af[mi] = *(const bf16x8*)(const void*)(&sb[aoff + mi * 512]);
#pragma unroll
        for (int jj = 0; jj < 4; ++jj)
            bfr[jj] = *(const bf16x8*)(const void*)(&sb[boff + jj * 512]);
        __builtin_amdgcn_s_setprio(1);
#pragma unroll
        for (int mi = 0; mi < 8; ++mi)
#pragma unroll
            for (int jj = 0; jj < 4; ++jj)
                acc[mi][jj] = __builtin_amdgcn_mfma_f32_16x16x32_bf16(
                    af[mi], bfr[jj], acc[mi][jj], 0, 0, 0);
        __builtin_amdgcn_s_setprio(0);
        if (kt + 1 < KT) {
            // counted wait: tile kt+1 must be resident; keep deeper prefetch in flight
            if (kt + 3 < KT)
                asm volatile("s_waitcnt vmcnt(8) lgkmcnt(0)\n\ts_barrier" ::: "memory");
            else if (kt + 2 < KT)
                asm volatile("s_waitcnt vmcnt(4) lgkmcnt(0)\n\ts_barrier" ::: "memory");
            else
                asm volatile("s_waitcnt vmcnt(0) lgkmcnt(0)\n\ts_barrier" ::: "memory");
        }
    }

    // ---- epilogue (C/D layout: col=lane&15, row=quad*4+reg) — in-register ----
    const int m_base = m0 + wm * 128 + quad * 4;
    if (EPI == 0) {
        if (tileN < 2) {
            const int o0 = tileN * 128 + wn * 32 + l15;
            const float bI0 = bias[o0],            bI1 = bias[o0 + 16];
            const float bH0 = bias[512 + o0],      bH1 = bias[512 + o0 + 16];
            const int q = (tileN * 4 + wn) * 16 + l15;      // u32 slot
#pragma unroll
            for (int mi = 0; mi < 8; ++mi) {
#pragma unroll
                for (int r = 0; r < 4; ++r) {
                    const int m = m_base + mi * 16 + r;
                    const float ig0 = sigm(acc[mi][0][r] + bI0) * fmaxf(acc[mi][2][r] + bH0, 0.f);
                    const float ig1 = sigm(acc[mi][1][r] + bI1) * fmaxf(acc[mi][3][r] + bH1, 0.f);
                    *(u32*)(void*)(Gout + (size_t)m * G2_ + 2 * q) = pack2h(ig0, ig1);
                }
            }
        } else {
            const int o0 = wn * 64 + l15;
            const float bF0 = bias[256 + o0],       bF1 = bias[256 + o0 + 16];
            const float bF2 = bias[256 + o0 + 32],  bF3 = bias[256 + o0 + 48];
            const int qA = wn * 32 + l15, qB = qA + 16;
#pragma unroll
            for (int mi = 0; mi < 8; ++mi) {
#pragma unroll
                for (int r = 0; r < 4; ++r) {
                    const int m = m_base + mi * 16 + r;
                    u16* row = Gout + (size_t)m * G2_ + 256;
                    *(u32*)(void*)(row + 2 * qA) =
                        pack2h(sigm(acc[mi][0][r] + bF0), sigm(acc[mi][1][r] + bF1));
                    *(u32*)(void*)(row + 2 * qB) =
                        pack2h(sigm(acc[mi][2][r] + bF2), sigm(acc[mi][3][r] + bF3));
                }
            }
        }
    } else {
        const int colb = wn * 64 + l15;
        float bb[4];
#pragma unroll
        for (int jj = 0; jj < 4; ++jj) bb[jj] = bias[colb + jj * 16];
#pragma unroll
        for (int mi = 0; mi < 8; ++mi) {
#pragma unroll
            for (int r = 0; r < 4; ++r) {
                const int m = m_base + mi * 16 + r;
                const u16* cp = cellbuf + (size_t)m * K_ + 256 + colb;
                float* op = Out + (size_t)m * N2_ + colb;
#pragma unroll
                for (int jj = 0; jj < 4; ++jj)
                    op[jj * 16] = sigm(acc[mi][jj][r] + bb[jj]) * bf2f(cp[jj * 16]);
            }
        }
    }
}

// ---- scan phase 1: local recurrence over 64 steps; 4 values/thread ----
// g' is pre-activated fp16 in slot order; recurrence is order-agnostic, so
// carries (cF/cC/cin) stay in storage order. grid: B*H*8 blocks x 256 thr.
__global__ __launch_bounds__(256) void scan_phase1(
    const u16* __restrict__ g2, float* __restrict__ cF, float* __restrict__ cC)
{
    const int blk = blockIdx.x;              // (b*8+h)*8 + chp
    const int chp = blk & 7, bh = blk >> 3;
    const int h = bh & 7, b = bh >> 3;
    const int t = threadIdx.x;
    const int ch = chp * 4 + (t >> 6);
    const int o = (t & 63) * 4;              // storage u16 offset
    float F[4] = {1.f, 1.f, 1.f, 1.f};
    float c[4] = {0.f, 0.f, 0.f, 0.f};
    for (int i = 0; i < 64; ++i) {
        const int s = ch * 64 + i;
        const size_t m = ((size_t)(b * S_ + s)) * H_ + h;
        const u16* gp = g2 + m * G2_;
        const uint2 igp = *(const uint2*)(const void*)(gp + o);
        const uint2 fgp = *(const uint2*)(const void*)(gp + 256 + o);
        const float f0 = h2f((u16)fgp.x), f1 = h2f((u16)(fgp.x >> 16));
        const float f2 = h2f((u16)fgp.y), f3 = h2f((u16)(fgp.y >> 16));
        c[0] = f0 * c[0] + h2f((u16)igp.x);         F[0] *= f0;
        c[1] = f1 * c[1] + h2f((u16)(igp.x >> 16)); F[1] *= f1;
        c[2] = f2 * c[2] + h2f((u16)igp.y);         F[2] *= f2;
        c[3] = f3 * c[3] + h2f((u16)(igp.y >> 16)); F[3] *= f3;
    }
    const size_t idx = ((size_t)(bh * 32 + ch)) * 256 + o;
    *(float4*)(void*)(cF + idx) = make_float4(F[0], F[1], F[2], F[3]);
    *(float4*)(void*)(cC + idx) = make_float4(c[0], c[1], c[2], c[3]);
}

// ---- scan carry combine (storage order; initcx needs real o) ----
__global__ __launch_bounds__(256) void scan_mid(
    const float* __restrict__ cF, const float* __restrict__ cC,
    const float* __restrict__ initcx, float* __restrict__ cin)
{
    const int bh = blockIdx.x;               // b*8 + h
    const int h = bh & 7;
    const int a = threadIdx.x;               // storage position
    const int q = a >> 1, hfl = a & 1;
    const int ro = ((q >> 4) << 5) + (q & 15) + (hfl << 4);  // real o
    float c = initcx[h * 256 + ro];
    for (int ch = 0; ch < 32; ++ch) {
        const size_t idx = ((size_t)(bh * 32 + ch)) * 256 + a;
        cin[idx] = c;
        c = cF[idx] * c + cC[idx];
    }
}

// ---- scan phase 2: replay; write cell bf16 (real o order) into x2 ----
__global__ __launch_bounds__(256) void scan_phase2(
    const u16* __restrict__ g2, const float* __restrict__ cin,
    u16* __restrict__ x2)
{
    const int blk = blockIdx.x;
    const int chp = blk & 7, bh = blk >> 3;
    const int h = bh & 7, b = bh >> 3;
    const int t = threadIdx.x;
    const int ch = chp * 4 + (t >> 6);
    const int z = t & 63;
    const int o = z * 4;                     // storage u16 offset
    // storage positions o..o+3 map to real o's: oA, oA+16, oA+1, oA+17
    const int oA = ((z >> 3) << 5) + ((z & 7) << 1);
    const size_t idx = ((size_t)(bh * 32 + ch)) * 256 + o;
    float4 c4 = *(const float4*)(const void*)(cin + idx);
    float c[4] = {c4.x, c4.y, c4.z, c4.w};
    for (int i = 0; i < 64; ++i) {
        const int s = ch * 64 + i;
        const size_t m = ((size_t)(b * S_ + s)) * H_ + h;
        const u16* gp = g2 + m * G2_;
        const uint2 igp = *(const uint2*)(const void*)(gp + o);
        const uint2 fgp = *(const uint2*)(const void*)(gp + 256 + o);
        const float f0 = h2f((u16)fgp.x), f1 = h2f((u16)(fgp.x >> 16));
        const float f2 = h2f((u16)fgp.y), f3 = h2f((u16)(fgp.y >> 16));
        c[0] = f0 * c[0] + h2f((u16)igp.x);
        c[1] = f1 * c[1] + h2f((u16)(igp.x >> 16));
        c[2] = f2 * c[2] + h2f((u16)igp.y);
        c[3] = f3 * c[3] + h2f((u16)(igp.y >> 16));
        u16* xr = x2 + m * K_ + 256;
        const u32 pkA = (u32)f2bf(c[0]) | ((u32)f2bf(c[2]) << 16);  // cols oA, oA+1
        const u32 pkB = (u32)f2bf(c[1]) | ((u32)f2bf(c[3]) << 16);  // cols oA+16, oA+17
        *(u32*)(void*)(xr + oA)      = pkA;
        *(u32*)(void*)(xr + oA + 16) = pkB;
    }
}

extern "C" void kernel_launch(void* const* d_in, const int* in_sizes, int n_in,
                              void* d_out, int out_size, void* d_ws, size_t ws_size,
                              hipStream_t stream)
{
    const float* X      = (const float*)d_in[0];
    const float* Whid   = (const float*)d_in[1];
    const float* bhid   = (const float*)d_in[2];
    const float* Wog    = (const float*)d_in[3];
    const float* bog    = (const float*)d_in[4];
    const float* lnw    = (const float*)d_in[5];
    const float* lnb    = (const float*)d_in[6];
    const float* initcx = (const float*)d_in[7];
    float* out = (float*)d_out;

    char* ws = (char*)d_ws;
    u16* x2   = (u16*)(ws + OFF_X2);
    u16* g    = (u16*)(ws + OFF_G);
    u16* WhB  = (u16*)(ws + OFF_WH);
    u16* WoB  = (u16*)(ws + OFF_WO);
    float* aux = (float*)(ws + OFF_AUX);
    float* cF  = (float*)(ws + OFF_CF);
    float* cC  = (float*)(ws + OFF_CC);
    float* cin = (float*)(ws + OFF_CIN);

    wconv_kernel<<<(N1_*K_ + 255) / 256, 256, 0, stream>>>(Whid, Wog, WhB, WoB);
    csum_phase1<<<B_ * CSCH, 256, 0, stream>>>(X, aux);
    csum_mid<<<64, 256, 0, stream>>>(aux);
    csum_phase2<<<B_ * CSCH, 256, 0, stream>>>(X, aux, lnw, lnb, x2);
    gemm_kernel<N1_, 0><<<(M_ / 256) * (N1_ / 256), 512, 0, stream>>>(
        x2, WhB, g, bhid, nullptr, nullptr);
    scan_phase1<<<B_ * H_ * 8, 256, 0, stream>>>(g, cF, cC);
    scan_mid<<<B_ * H_, 256, 0, stream>>>(cF, cC, initcx, cin);
    scan_phase2<<<B_ * H_ * 8, 256, 0, stream>>>(g, cin, x2);
    gemm_kernel<N2_, 1><<<(M_ / 256) * (N2_ / 256), 512, 0, stream>>>(
        x2, WoB, nullptr, bog, x2, out);
}

// Round 4
// 557.133 us; speedup vs baseline: 1.1528x; 1.0093x over previous
//
#include <hip/hip_runtime.h>

typedef unsigned short u16;
typedef unsigned int u32;

typedef __attribute__((ext_vector_type(8))) short bf16x8;
typedef __attribute__((ext_vector_type(4))) float f32x4;

#define B_ 8
#define S_ 2048
#define H_ 8
#define ID_ 256
#define OD_ 256
#define K_ 512
#define M_ (B_*S_*H_)   /* 131072 */
#define N1_ 768
#define N2_ 256
#define G2_ 512          /* activated-gate tensor width: [ig(256) | f(256)] fp16 */

#define CSCH 64            /* cumsum chunks over S */
#define CSST (S_/CSCH)     /* 32 steps per chunk */

// ---- workspace layout (bytes) ----
#define OFF_X2   (0ull)
#define SZ_X2    ((unsigned long long)M_*K_*2)        /* 134,217,728 */
#define OFF_G    (OFF_X2 + SZ_X2)
#define SZ_G     ((unsigned long long)M_*G2_*2)       /* 134,217,728 */
#define OFF_WH   (OFF_G + SZ_G)
#define SZ_WH    ((unsigned long long)N1_*K_*2)
#define OFF_WO   (OFF_WH + SZ_WH)
#define SZ_WO    ((unsigned long long)N2_*K_*2)
#define OFF_AUX  (OFF_WO + SZ_WO)
#define SZ_AUX   ((unsigned long long)B_*CSCH*2048*4)
#define OFF_CF   (OFF_AUX + SZ_AUX)
#define SZ_CARR  ((unsigned long long)B_*H_*32*256*4)
#define OFF_CC   (OFF_CF + SZ_CARR)
#define OFF_CIN  (OFF_CC + SZ_CARR)

__device__ __forceinline__ u16 f2bf(float f) {
    union { float f; u32 u; } v; v.f = f;
    u32 u = v.u;
    u += 0x7fffu + ((u >> 16) & 1u);   // round-to-nearest-even
    return (u16)(u >> 16);
}
__device__ __forceinline__ float bf2f(u16 h) {
    union { u32 u; float f; } v; v.u = ((u32)h) << 16;
    return v.f;
}
__device__ __forceinline__ u32 pack2h(float a, float b) {
    union { _Float16 h; u16 u; } x, y;
    x.h = (_Float16)a; y.h = (_Float16)b;
    return (u32)x.u | ((u32)y.u << 16);
}
__device__ __forceinline__ float h2f(u16 u) {
    union { u16 u; _Float16 h; } v; v.u = u;
    return (float)v.h;
}
__device__ __forceinline__ float sigm(float x) {
    return 1.0f / (1.0f + __expf(-x));
}

// async 16B global->LDS DMA. LDS dest = wave-uniform base + lane*16.
__device__ __forceinline__ void gld16(const void* g, void* l) {
    __builtin_amdgcn_global_load_lds(
        (const __attribute__((address_space(1))) void*)g,
        (__attribute__((address_space(3))) void*)l, 16, 0, 0);
}

// W_hid row permutation (256-wide tiles, 8 waves of 64 cols).
// Pair tiles t=0,1 (n<512): c=n&255, wn=c>>6, jj=(c>>4)&3, l=c&15
//   o = t*128 + wn*32 + (jj&1)*16 + l
//   jj in {0,1} -> igate row o ; jj in {2,3} -> hidden row 512+o
//   => per lane: ig_o = sig(acc[jj]) * relu(acc[jj+2])  (same lane, in-register)
// F tile t=2: o = n-512 -> fgate row 256+o (natural)
__device__ __forceinline__ int whid_src_row(int n) {
    const int t = n >> 8, c = n & 255;
    if (t < 2) {
        const int wn = c >> 6, jj = (c >> 4) & 3, l = c & 15;
        const int o = t * 128 + wn * 32 + (jj & 1) * 16 + l;
        return (jj < 2) ? o : (512 + o);
    }
    return 256 + (n - 512);
}

// ---- 0: weights fp32 -> bf16 (W_hid rows permuted) ----
__global__ __launch_bounds__(256) void wconv_kernel(
    const float* __restrict__ Whid, const float* __restrict__ Wog,
    u16* __restrict__ WhB, u16* __restrict__ WoB)
{
    int idx = blockIdx.x * 256 + threadIdx.x;
    if (idx < N1_*K_) {
        const int n = idx >> 9, k = idx & 511;
        WhB[idx] = f2bf(Whid[(size_t)whid_src_row(n) * K_ + k]);
    }
    if (idx < N2_*K_) WoB[idx] = f2bf(Wog[idx]);
}

// ---- 1: cumsum phase 1 — per-(b,chunk) local totals over CSST s-steps ----
__global__ __launch_bounds__(256) void csum_phase1(
    const float* __restrict__ X, float* __restrict__ aux)
{
    const int bch = blockIdx.x;          // b*CSCH + ch
    const int b = bch / CSCH, ch = bch % CSCH;
    const int t = threadIdx.x;
    float acc[8];
#pragma unroll
    for (int h = 0; h < 8; ++h) acc[h] = 0.f;
    for (int i = 0; i < CSST; ++i) {
        const int s = ch * CSST + i;
        const float* xp = X + ((size_t)(b * S_ + s)) * 2048 + t;
#pragma unroll
        for (int h = 0; h < 8; ++h) acc[h] += xp[h * 256];
    }
    float* ap = aux + (size_t)bch * 2048 + t;
#pragma unroll
    for (int h = 0; h < 8; ++h) ap[h * 256] = acc[h];
}

// ---- 2: cumsum carry — exclusive prefix over CSCH chunks, in place ----
__global__ __launch_bounds__(256) void csum_mid(float* __restrict__ aux)
{
    const int idx = blockIdx.x * 256 + threadIdx.x;
    const int b = idx >> 11, c = idx & 2047;
    float run = 0.f;
    for (int ch = 0; ch < CSCH; ++ch) {
        float* p = aux + ((size_t)(b * CSCH + ch)) * 2048 + c;
        float v = *p; *p = run; run += v;
    }
}

// ---- 3: cumsum phase 2 — replay + LayerNorm + pack x2 bf16 ----
__global__ __launch_bounds__(256) void csum_phase2(
    const float* __restrict__ X, const float* __restrict__ aux,
    const float* __restrict__ lnw, const float* __restrict__ lnb,
    u16* __restrict__ x2)
{
    const int bch = blockIdx.x;
    const int b = bch / CSCH, ch = bch % CSCH;
    const int t = threadIdx.x;
    float c[8], wv[8], bv[8];
#pragma unroll
    for (int h = 0; h < 8; ++h) {
        c[h]  = aux[(size_t)bch * 2048 + h * 256 + t];
        wv[h] = lnw[h * 256 + t];
        bv[h] = lnb[h * 256 + t];
    }
    __shared__ float red[2][4];
    for (int i = 0; i < CSST; ++i) {
        const int s = ch * CSST + i;
        const float* xp = X + ((size_t)(b * S_ + s)) * 2048 + t;
        float xa[8];
#pragma unroll
        for (int h = 0; h < 8; ++h) { xa[h] = xp[h * 256]; c[h] += xa[h]; }
        float sx = 0.f, sq = 0.f;
#pragma unroll
        for (int h = 0; h < 8; ++h) { sx += c[h]; sq += c[h] * c[h]; }
#pragma unroll
        for (int off = 32; off >= 1; off >>= 1) {
            sx += __shfl_down(sx, (unsigned)off);
            sq += __shfl_down(sq, (unsigned)off);
        }
        const int wid = t >> 6;
        if ((t & 63) == 0) { red[0][wid] = sx; red[1][wid] = sq; }
        __syncthreads();
        const float tsx = red[0][0] + red[0][1] + red[0][2] + red[0][3];
        const float tsq = red[1][0] + red[1][1] + red[1][2] + red[1][3];
        __syncthreads();
        const float mean = tsx * (1.f / 2048.f);
        const float var  = tsq * (1.f / 2048.f) - mean * mean;
        const float rstd = rsqrtf(var + 1e-6f);
        const size_t mrow = ((size_t)(b * S_ + s)) * H_;
#pragma unroll
        for (int h = 0; h < 8; ++h) {
            u16* row = x2 + (mrow + h) * (size_t)K_;
            row[t]       = f2bf(xa[h]);
            row[256 + t] = f2bf((c[h] - mean) * rstd * wv[h] + bv[h]);
        }
    }
}

// ---- GEMM: C[m,n] = sum_k A[m,k] * W[n,k], A/W bf16 row-major (ld=512) ----
// 256x256 tile, BK=32, 512 thr = 8 waves (2M x 4N), 128x64 out per wave,
// acc[8][4] via mfma_16x16x32_bf16.
// Deep pipeline: 4-buffer LDS ring (128 KiB), depth-3 prefetch with
// global_load_lds; counted s_waitcnt vmcnt (never 0 mid-loop) + RAW s_barrier.
// Inner loop is split into TWO phases per K-step (template-style role split):
//   ph1: read B(4)+A-lo(4), stage A-half(kt+3), barrier, lgkmcnt(0),
//        setprio(1), 16 MFMA, setprio(0), barrier
//   ph2: read A-hi(4), stage B-half(kt+3), barrier, lgkmcnt(0),
//        setprio(1), 16 MFMA, setprio(0), vmcnt(8) + barrier
// LDS rows are 64B (32 bf16); conflict swizzle: phys 16B chunk = c ^ ((row>>1)&3),
// applied on the GLOBAL source side for staging (gld16 dest must be linear)
// and on the read side for ds_read_b128.
// EPI==0 (GATE): in-register activations, write fp16 g' slots (see wconv map).
// EPI==1 (OG): in-register fp32 out = sigmoid(x+b)*cell.
template<int N, int EPI>
__global__ __launch_bounds__(512, 2) void gemm_kernel(
    const u16* __restrict__ A, const u16* __restrict__ Bw,
    u16* __restrict__ Gout, const float* __restrict__ bias,
    const u16* __restrict__ cellbuf, float* __restrict__ Out)
{
    constexpr int NT = N / 256;
    constexpr int KT = K_ / 32;     // 16 K-tiles
    const int blk = blockIdx.x;
    const int xcd = blk & 7;
    const int j = blk >> 3;
    const int tileN = j % NT;
    const int tileM = (j / NT) * 8 + xcd;
    const int m0 = tileM * 256, n0 = tileN * 256;
    const int tid = threadIdx.x;
    const int lane = tid & 63;
    const int w = tid >> 6;                 // wave 0..7
    const int wm = w >> 2, wn = w & 3;      // 2 x 4
    const int l15 = lane & 15, quad = lane >> 4;

    // 4 ring buffers x (A 256x32 + B 256x32) bf16 = 4 x 32 KB = 128 KB
    __shared__ __align__(16) u16 smem[4 * 16384];

    // --- staging geometry (per thread: 2 A-loads + 2 B-loads per K-tile) ---
    const int srow   = lane >> 2;                                  // 0..15
    const int schunk = ((lane & 3) ^ ((lane >> 3) & 3)) * 8;       // swizzled src col
    const u16* gA0 = A  + (size_t)(m0 + w * 32      + srow) * K_ + schunk;
    const u16* gA1 = A  + (size_t)(m0 + w * 32 + 16 + srow) * K_ + schunk;
    const u16* gB0 = Bw + (size_t)(n0 + w * 32      + srow) * K_ + schunk;
    const u16* gB1 = Bw + (size_t)(n0 + w * 32 + 16 + srow) * K_ + schunk;

    auto STAGE_A = [&](int bufb, int kt) {
        u16* sb = smem + bufb * 16384;
        gld16(gA0 + kt * 32, sb + (w * 32) * 32);
        gld16(gA1 + kt * 32, sb + (w * 32 + 16) * 32);
    };
    auto STAGE_B = [&](int bufb, int kt) {
        u16* sb = smem + bufb * 16384;
        gld16(gB0 + kt * 32, sb + 8192 + (w * 32) * 32);
        gld16(gB1 + kt * 32, sb + 8192 + (w * 32 + 16) * 32);
    };

    // --- fragment read geometry ---
    const int swz  = (quad ^ ((l15 >> 1) & 3)) * 8;                // swizzled chunk
    const int aoff = (wm * 128 + l15) * 32 + swz;                  // + mi*512
    const int boff = 8192 + (wn * 64 + l15) * 32 + swz;            // + jj*512

    f32x4 acc[8][4];
    const f32x4 zero4 = {0.f, 0.f, 0.f, 0.f};
#pragma unroll
    for (int mi = 0; mi < 8; ++mi)
#pragma unroll
        for (int jj = 0; jj < 4; ++jj) acc[mi][jj] = zero4;

    // prologue: stage tiles 0,1,2; wait tile 0 (8 = tiles 1,2 still in flight)
    STAGE_A(0, 0); STAGE_B(0, 0);
    STAGE_A(1, 1); STAGE_B(1, 1);
    STAGE_A(2, 2); STAGE_B(2, 2);
    asm volatile("s_waitcnt vmcnt(8)\n\ts_barrier" ::: "memory");

#pragma unroll
    for (int kt = 0; kt < KT; ++kt) {
        const int cur = kt & 3;
        const u16* sb = smem + cur * 16384;
        bf16x8 af0[4], af1[4], bfr[4];

        // ---- phase 1: issue B + A-low reads; stage A-half of kt+3 ----
#pragma unroll
        for (int jj = 0; jj < 4; ++jj)
            bfr[jj] = *(const bf16x8*)(const void*)(&sb[boff + jj * 512]);
#pragma unroll
        for (int mi = 0; mi < 4; ++mi)
            af0[mi] = *(const bf16x8*)(const void*)(&sb[aoff + mi * 512]);
        if (kt + 3 < KT) STAGE_A((kt + 3) & 3, kt + 3);
        asm volatile("s_barrier" ::: "memory");
        asm volatile("s_waitcnt lgkmcnt(0)" ::: "memory");
        __builtin_amdgcn_sched_barrier(0);
        __builtin_amdgcn_s_setprio(1);
#pragma unroll
        for (int mi = 0; mi < 4; ++mi)
#pragma unroll
            for (int jj = 0; jj < 4; ++jj)
                acc[mi][jj] = __builtin_amdgcn_mfma_f32_16x16x32_bf16(
                    af0[mi], bfr[jj], acc[mi][jj], 0, 0, 0);
        __builtin_amdgcn_s_setprio(0);
        asm volatile("s_barrier" ::: "memory");

        // ---- phase 2: issue A-high reads; stage B-half of kt+3 ----
#pragma unroll
        for (int mi = 0; mi < 4; ++mi)
            af1[mi] = *(const bf16x8*)(const void*)(&sb[aoff + (mi + 4) * 512]);
        if (kt + 3 < KT) STAGE_B((kt + 3) & 3, kt + 3);
        asm volatile("s_barrier" ::: "memory");
        asm volatile("s_waitcnt lgkmcnt(0)" ::: "memory");
        __builtin_amdgcn_sched_barrier(0);
        __builtin_amdgcn_s_setprio(1);
#pragma unroll
        for (int mi = 0; mi < 4; ++mi)
#pragma unroll
            for (int jj = 0; jj < 4; ++jj)
                acc[mi + 4][jj] = __builtin_amdgcn_mfma_f32_16x16x32_bf16(
                    af1[mi], bfr[jj], acc[mi + 4][jj], 0, 0, 0);
        __builtin_amdgcn_s_setprio(0);

        // end-of-kt: counted wait — tile kt+1 must be resident; keep deeper
        // prefetch (tiles kt+2, kt+3 = 8 loads/thread) in flight
        if (kt + 1 < KT) {
            if (kt + 3 < KT)
                asm volatile("s_waitcnt vmcnt(8)\n\ts_barrier" ::: "memory");
            else if (kt + 2 < KT)
                asm volatile("s_waitcnt vmcnt(4)\n\ts_barrier" ::: "memory");
            else
                asm volatile("s_waitcnt vmcnt(0)\n\ts_barrier" ::: "memory");
        }
    }

    // ---- epilogue (C/D layout: col=lane&15, row=quad*4+reg) — in-register ----
    const int m_base = m0 + wm * 128 + quad * 4;
    if (EPI == 0) {
        if (tileN < 2) {
            const int o0 = tileN * 128 + wn * 32 + l15;
            const float bI0 = bias[o0],            bI1 = bias[o0 + 16];
            const float bH0 = bias[512 + o0],      bH1 = bias[512 + o0 + 16];
            const int q = (tileN * 4 + wn) * 16 + l15;      // u32 slot
#pragma unroll
            for (int mi = 0; mi < 8; ++mi) {
#pragma unroll
                for (int r = 0; r < 4; ++r) {
                    const int m = m_base + mi * 16 + r;
                    const float ig0 = sigm(acc[mi][0][r] + bI0) * fmaxf(acc[mi][2][r] + bH0, 0.f);
                    const float ig1 = sigm(acc[mi][1][r] + bI1) * fmaxf(acc[mi][3][r] + bH1, 0.f);
                    *(u32*)(void*)(Gout + (size_t)m * G2_ + 2 * q) = pack2h(ig0, ig1);
                }
            }
        } else {
            const int o0 = wn * 64 + l15;
            const float bF0 = bias[256 + o0],       bF1 = bias[256 + o0 + 16];
            const float bF2 = bias[256 + o0 + 32],  bF3 = bias[256 + o0 + 48];
            const int qA = wn * 32 + l15, qB = qA + 16;
#pragma unroll
            for (int mi = 0; mi < 8; ++mi) {
#pragma unroll
                for (int r = 0; r < 4; ++r) {
                    const int m = m_base + mi * 16 + r;
                    u16* row = Gout + (size_t)m * G2_ + 256;
                    *(u32*)(void*)(row + 2 * qA) =
                        pack2h(sigm(acc[mi][0][r] + bF0), sigm(acc[mi][1][r] + bF1));
                    *(u32*)(void*)(row + 2 * qB) =
                        pack2h(sigm(acc[mi][2][r] + bF2), sigm(acc[mi][3][r] + bF3));
                }
            }
        }
    } else {
        const int colb = wn * 64 + l15;
        float bb[4];
#pragma unroll
        for (int jj = 0; jj < 4; ++jj) bb[jj] = bias[colb + jj * 16];
#pragma unroll
        for (int mi = 0; mi < 8; ++mi) {
#pragma unroll
            for (int r = 0; r < 4; ++r) {
                const int m = m_base + mi * 16 + r;
                const u16* cp = cellbuf + (size_t)m * K_ + 256 + colb;
                float* op = Out + (size_t)m * N2_ + colb;
#pragma unroll
                for (int jj = 0; jj < 4; ++jj)
                    op[jj * 16] = sigm(acc[mi][jj][r] + bb[jj]) * bf2f(cp[jj * 16]);
            }
        }
    }
}

// ---- scan phase 1: local recurrence over 64 steps; 4 values/thread ----
// g' is pre-activated fp16 in slot order; recurrence is order-agnostic, so
// carries (cF/cC/cin) stay in storage order. grid: B*H*8 blocks x 256 thr.
__global__ __launch_bounds__(256) void scan_phase1(
    const u16* __restrict__ g2, float* __restrict__ cF, float* __restrict__ cC)
{
    const int blk = blockIdx.x;              // (b*8+h)*8 + chp
    const int chp = blk & 7, bh = blk >> 3;
    const int h = bh & 7, b = bh >> 3;
    const int t = threadIdx.x;
    const int ch = chp * 4 + (t >> 6);
    const int o = (t & 63) * 4;              // storage u16 offset
    float F[4] = {1.f, 1.f, 1.f, 1.f};
    float c[4] = {0.f, 0.f, 0.f, 0.f};
    for (int i = 0; i < 64; ++i) {
        const int s = ch * 64 + i;
        const size_t m = ((size_t)(b * S_ + s)) * H_ + h;
        const u16* gp = g2 + m * G2_;
        const uint2 igp = *(const uint2*)(const void*)(gp + o);
        const uint2 fgp = *(const uint2*)(const void*)(gp + 256 + o);
        const float f0 = h2f((u16)fgp.x), f1 = h2f((u16)(fgp.x >> 16));
        const float f2 = h2f((u16)fgp.y), f3 = h2f((u16)(fgp.y >> 16));
        c[0] = f0 * c[0] + h2f((u16)igp.x);         F[0] *= f0;
        c[1] = f1 * c[1] + h2f((u16)(igp.x >> 16)); F[1] *= f1;
        c[2] = f2 * c[2] + h2f((u16)igp.y);         F[2] *= f2;
        c[3] = f3 * c[3] + h2f((u16)(igp.y >> 16)); F[3] *= f3;
    }
    const size_t idx = ((size_t)(bh * 32 + ch)) * 256 + o;
    *(float4*)(void*)(cF + idx) = make_float4(F[0], F[1], F[2], F[3]);
    *(float4*)(void*)(cC + idx) = make_float4(c[0], c[1], c[2], c[3]);
}

// ---- scan carry combine (storage order; initcx needs real o) ----
__global__ __launch_bounds__(256) void scan_mid(
    const float* __restrict__ cF, const float* __restrict__ cC,
    const float* __restrict__ initcx, float* __restrict__ cin)
{
    const int bh = blockIdx.x;               // b*8 + h
    const int h = bh & 7;
    const int a = threadIdx.x;               // storage position
    const int q = a >> 1, hfl = a & 1;
    const int ro = ((q >> 4) << 5) + (q & 15) + (hfl << 4);  // real o
    float c = initcx[h * 256 + ro];
    for (int ch = 0; ch < 32; ++ch) {
        const size_t idx = ((size_t)(bh * 32 + ch)) * 256 + a;
        cin[idx] = c;
        c = cF[idx] * c + cC[idx];
    }
}

// ---- scan phase 2: replay; write cell bf16 (real o order) into x2 ----
__global__ __launch_bounds__(256) void scan_phase2(
    const u16* __restrict__ g2, const float* __restrict__ cin,
    u16* __restrict__ x2)
{
    const int blk = blockIdx.x;
    const int chp = blk & 7, bh = blk >> 3;
    const int h = bh & 7, b = bh >> 3;
    const int t = threadIdx.x;
    const int ch = chp * 4 + (t >> 6);
    const int z = t & 63;
    const int o = z * 4;                     // storage u16 offset
    // storage positions o..o+3 map to real o's: oA, oA+16, oA+1, oA+17
    const int oA = ((z >> 3) << 5) + ((z & 7) << 1);
    const size_t idx = ((size_t)(bh * 32 + ch)) * 256 + o;
    float4 c4 = *(const float4*)(const void*)(cin + idx);
    float c[4] = {c4.x, c4.y, c4.z, c4.w};
    for (int i = 0; i < 64; ++i) {
        const int s = ch * 64 + i;
        const size_t m = ((size_t)(b * S_ + s)) * H_ + h;
        const u16* gp = g2 + m * G2_;
        const uint2 igp = *(const uint2*)(const void*)(gp + o);
        const uint2 fgp = *(const uint2*)(const void*)(gp + 256 + o);
        const float f0 = h2f((u16)fgp.x), f1 = h2f((u16)(fgp.x >> 16));
        const float f2 = h2f((u16)fgp.y), f3 = h2f((u16)(fgp.y >> 16));
        c[0] = f0 * c[0] + h2f((u16)igp.x);
        c[1] = f1 * c[1] + h2f((u16)(igp.x >> 16));
        c[2] = f2 * c[2] + h2f((u16)igp.y);
        c[3] = f3 * c[3] + h2f((u16)(igp.y >> 16));
        u16* xr = x2 + m * K_ + 256;
        const u32 pkA = (u32)f2bf(c[0]) | ((u32)f2bf(c[2]) << 16);  // cols oA, oA+1
        const u32 pkB = (u32)f2bf(c[1]) | ((u32)f2bf(c[3]) << 16);  // cols oA+16, oA+17
        *(u32*)(void*)(xr + oA)      = pkA;
        *(u32*)(void*)(xr + oA + 16) = pkB;
    }
}

extern "C" void kernel_launch(void* const* d_in, const int* in_sizes, int n_in,
                              void* d_out, int out_size, void* d_ws, size_t ws_size,
                              hipStream_t stream)
{
    const float* X      = (const float*)d_in[0];
    const float* Whid   = (const float*)d_in[1];
    const float* bhid   = (const float*)d_in[2];
    const float* Wog    = (const float*)d_in[3];
    const float* bog    = (const float*)d_in[4];
    const float* lnw    = (const float*)d_in[5];
    const float* lnb    = (const float*)d_in[6];
    const float* initcx = (const float*)d_in[7];
    float* out = (float*)d_out;

    char* ws = (char*)d_ws;
    u16* x2   = (u16*)(ws + OFF_X2);
    u16* g    = (u16*)(ws + OFF_G);
    u16* WhB  = (u16*)(ws + OFF_WH);
    u16* WoB  = (u16*)(ws + OFF_WO);
    float* aux = (float*)(ws + OFF_AUX);
    float* cF  = (float*)(ws + OFF_CF);
    float* cC  = (float*)(ws + OFF_CC);
    float* cin = (float*)(ws + OFF_CIN);

    wconv_kernel<<<(N1_*K_ + 255) / 256, 256, 0, stream>>>(Whid, Wog, WhB, WoB);
    csum_phase1<<<B_ * CSCH, 256, 0, stream>>>(X, aux);
    csum_mid<<<64, 256, 0, stream>>>(aux);
    csum_phase2<<<B_ * CSCH, 256, 0, stream>>>(X, aux, lnw, lnb, x2);
    gemm_kernel<N1_, 0><<<(M_ / 256) * (N1_ / 256), 512, 0, stream>>>(
        x2, WhB, g, bhid, nullptr, nullptr);
    scan_phase1<<<B_ * H_ * 8, 256, 0, stream>>>(g, cF, cC);
    scan_mid<<<B_ * H_, 256, 0, stream>>>(cF, cC, initcx, cin);
    scan_phase2<<<B_ * H_ * 8, 256, 0, stream>>>(g, cin, x2);
    gemm_kernel<N2_, 1><<<(M_ / 256) * (N2_ / 256), 512, 0, stream>>>(
        x2, WoB, nullptr, bog, x2, out);
}